// Round 9
// baseline (243.718 us; speedup 1.0000x reference)
//
#include <hip/hip_runtime.h>

// LowRankRotatedSpaceIntervention — v9: contiguous-1KB-per-instruction.
// out[b,:] = base[b,:] + (mask_b . ((source[b,:]-base[b,:]) @ W)) @ W^T
// B=16384, D=4096, R=64, 8 partitions of 8, 4 selected per row.
//
// R1-R8: BW pinned 1.8-2.9 TB/s across occupancy/staging/pipelining variants.
// Shared invariant: every VMEM instr touched 4 rows x 256B at 16KB stride --
// 16KB = 0 mod channel period, so each instr/chunk concentrated on ~1 HBM
// channel slot. v8's cross-block stagger (+11%) confirmed the channel theory
// but left per-instruction concentration. v9: EVERY phase-1 stage, phase-2
// base re-read and store is one contiguous 1KB span of a single row
// (64 lanes x 16B), like the 6.3 TB/s memcpy. Block-cooperative superchunks
// (16 rows x 1KB x {base,src} = 32KB, double-buffered), exact-counted vmcnt
// (v7 mechanics: all loop VMEM = global_load_lds builtins + one asm wload),
// raw s_barrier + manual lgkmcnt (no __syncthreads drain in the K-loop).
// A-frag reads conflict-free via source-side XOR ((row&7)<<4) inside the 1KB.

#define D_DIM 4096
#define R_DIM 64
#define BM    16
#define NSC   16               // 16 superchunks x 256 floats = 4096

typedef short bf16vec8 __attribute__((ext_vector_type(8)));
typedef float f32x4v  __attribute__((ext_vector_type(4)));
typedef unsigned int u32x4 __attribute__((ext_vector_type(4)));

// LDS: 2 staging buffers x 32KB ([16][1KB] base, [16][1KB] src), then rm.
#define BUFSZ       32768
#define OFF_RM      65536      // [16][72] bf16 = 2304 B
#define SMEM_BYTES  67840      // 2 blocks/CU

#define VMWAIT(N)                                              \
  do {                                                         \
    asm volatile("s_waitcnt vmcnt(" #N ")" ::: "memory");      \
    __builtin_amdgcn_sched_barrier(0);                         \
  } while (0)
#define LGKM0()                                                \
  do {                                                         \
    asm volatile("s_waitcnt lgkmcnt(0)" ::: "memory");         \
    __builtin_amdgcn_sched_barrier(0);                         \
  } while (0)
#define BAR()                                                  \
  do {                                                         \
    __builtin_amdgcn_s_barrier();                              \
    __builtin_amdgcn_sched_barrier(0);                         \
  } while (0)

__device__ __forceinline__ unsigned int f2bf_u(float f) {
  unsigned int u = __builtin_bit_cast(unsigned int, f);
  return (u + 0x7fffu + ((u >> 16) & 1u)) >> 16;   // RNE
}
__device__ __forceinline__ unsigned int pack2bf(float a, float b) {
  return f2bf_u(a) | (f2bf_u(b) << 16);
}
__device__ __forceinline__ void async_ld16(const void* gp, void* lp) {
  __builtin_amdgcn_global_load_lds(
      (const __attribute__((address_space(1))) void*)gp,
      (__attribute__((address_space(3))) void*)lp, 16, 0, 0);
}

__global__ __launch_bounds__(256)
void lrri_prep(const float* __restrict__ W, unsigned short* __restrict__ Wt,
               unsigned short* __restrict__ Wb) {
  const int idx = blockIdx.x * blockDim.x + threadIdx.x;   // 0..65535
  const int k = idx >> 4;
  const int j = (idx & 15) * 4;
  float4 w = *(const float4*)(W + (size_t)k * R_DIM + j);
  ushort4 p;
  p.x = (unsigned short)f2bf_u(w.x);
  p.y = (unsigned short)f2bf_u(w.y);
  p.z = (unsigned short)f2bf_u(w.z);
  p.w = (unsigned short)f2bf_u(w.w);
  *(ushort4*)(Wb + (size_t)k * R_DIM + j) = p;     // [4096][64] bf16
  Wt[(size_t)(j + 0) * D_DIM + k] = p.x;           // [64][4096] bf16
  Wt[(size_t)(j + 1) * D_DIM + k] = p.y;
  Wt[(size_t)(j + 2) * D_DIM + k] = p.z;
  Wt[(size_t)(j + 3) * D_DIM + k] = p.w;
}

template<bool USE_WS>
__global__ __launch_bounds__(256, 2)
void lrri_fused(const float* __restrict__ base, const float* __restrict__ srcp,
                const float* __restrict__ W, const int* __restrict__ subs,
                const unsigned short* __restrict__ Wt_bf,   // [64][4096]
                const unsigned short* __restrict__ Wb_bf,   // [4096][64]
                float* __restrict__ out)
{
  __shared__ __align__(16) unsigned char smem[SMEM_BYTES];
  const int tid  = threadIdx.x;
  const int wave = tid >> 6;             // 0..3: K-quarter owner / row group
  const int lane = tid & 63;
  const int l4   = lane & 15;
  const int g    = lane >> 4;
  const long rowbase = (long)blockIdx.x * BM;
  const int off1 = (blockIdx.x * 7) & 15;   // phase-1 superchunk stagger
  const int off2 = (blockIdx.x * 5) & 15;   // phase-2 superchunk stagger

  // stage logical superchunk i into buf[i&1]: wave stages rows wave*4..+3,
  // both arrays; each async_ld16 = one contiguous 1KB row-window (source
  // XOR-permuted within the window by (row&7)<<4 for conflict-free reads).
  auto stage = [&](int i) {
    const int sc = (i + off1) & 15;
    unsigned char* buf = smem + (i & 1) * BUFSZ;
    const unsigned lb = (unsigned)(lane * 16);
    #pragma unroll
    for (int q = 0; q < 4; ++q) {
      const int r = wave * 4 + q;
      const unsigned sw = (unsigned)((r & 7) << 4);
      const long goff = (rowbase + r) * (long)D_DIM + sc * 256 + ((lb ^ sw) >> 2);
      async_ld16(base + goff, buf + r * 1024);
      async_ld16(srcp + goff, buf + 16384 + r * 1024);
    }
  };

  // v7-proven asm block: 8 order-pinned global_load_dwordx4 of W fragments.
  auto wload = [&](u32x4 (&dst)[8], int kb) {
    const char* wbp = (const char*)Wt_bf + (size_t)kb * 2 + l4 * 8192 + g * 16;
    const char* a0 = wbp;
    const char* a1 = wbp + 16 * 8192;
    const char* a2 = wbp + 32 * 8192;
    const char* a3 = wbp + 48 * 8192;
    asm volatile(
        "global_load_dwordx4 %0, %8, off\n\t"
        "global_load_dwordx4 %1, %8, off offset:64\n\t"
        "global_load_dwordx4 %2, %9, off\n\t"
        "global_load_dwordx4 %3, %9, off offset:64\n\t"
        "global_load_dwordx4 %4, %10, off\n\t"
        "global_load_dwordx4 %5, %10, off offset:64\n\t"
        "global_load_dwordx4 %6, %11, off\n\t"
        "global_load_dwordx4 %7, %11, off offset:64"
        : "=&v"(dst[0]), "=&v"(dst[1]), "=&v"(dst[2]), "=&v"(dst[3]),
          "=&v"(dst[4]), "=&v"(dst[5]), "=&v"(dst[6]), "=&v"(dst[7])
        : "v"(a0), "v"(a1), "v"(a2), "v"(a3)
        : "memory");
  };

  f32x4v acc[4];
  #pragma unroll
  for (int t = 0; t < 4; ++t) acc[t] = (f32x4v){0.f, 0.f, 0.f, 0.f};

  const int kq = wave * 64;       // this wave's K-quarter within a superchunk

  // compute logical superchunk i from buf[i&1], wave's 64-float K-window
  auto compute = [&](int i, const u32x4 (&wf)[8]) {
    const unsigned char* buf = smem + (i & 1) * BUFSZ;
    const unsigned sw = (unsigned)((l4 & 7) << 4);
    u32x4 af[2];
    #pragma unroll
    for (int s = 0; s < 2; ++s) {
      const unsigned cB = (unsigned)(wave * 256 + s * 128 + g * 32);
      const unsigned cb0 = cB ^ sw, cb1 = (cB + 16) ^ sw;
      float4 fb0 = *(const float4*)(buf + l4 * 1024 + cb0);
      float4 fb1 = *(const float4*)(buf + l4 * 1024 + cb1);
      float4 fs0 = *(const float4*)(buf + 16384 + l4 * 1024 + cb0);
      float4 fs1 = *(const float4*)(buf + 16384 + l4 * 1024 + cb1);
      af[s].x = pack2bf(fs0.x - fb0.x, fs0.y - fb0.y);
      af[s].y = pack2bf(fs0.z - fb0.z, fs0.w - fb0.w);
      af[s].z = pack2bf(fs1.x - fb1.x, fs1.y - fb1.y);
      af[s].w = pack2bf(fs1.z - fb1.z, fs1.w - fb1.w);
    }
    #pragma unroll
    for (int t = 0; t < 4; ++t)
      #pragma unroll
      for (int s = 0; s < 2; ++s)
        acc[t] = __builtin_amdgcn_mfma_f32_16x16x32_bf16(
            __builtin_bit_cast(bf16vec8, af[s]),
            __builtin_bit_cast(bf16vec8, wf[t * 2 + s]), acc[t], 0, 0, 0);
  };

  auto kb_of = [&](int i) { return ((i + off1) & 15) * 256 + kq; };

  // ---------------- Phase 1 -----------------------------------------------
  if constexpr (USE_WS) {
    u32x4 wbA[8], wbB[8];
    stage(0); wload(wbA, kb_of(0));                 // queue: s0(8) W0(8)
    #pragma unroll 1
    for (int i = 0; i < 14; i += 2) {
      LGKM0(); BAR();                               // buf[(i+1)&1] free
      stage(i + 1); wload(wbB, kb_of(i + 1));       // queue 32
      VMWAIT(16);                                   // drains s(i), W(i)
      BAR();
      compute(i, wbA);
      LGKM0(); BAR();
      stage(i + 2); wload(wbA, kb_of(i + 2));
      VMWAIT(16);
      BAR();
      compute(i + 1, wbB);
    }
    LGKM0(); BAR();
    stage(15); wload(wbB, kb_of(15));
    VMWAIT(16);
    BAR();
    compute(14, wbA);
    LGKM0(); BAR();
    VMWAIT(0);
    BAR();
    compute(15, wbB);
  } else {
    // fallback: serial, full drain each superchunk (compiler W loads safe)
    #pragma unroll 1
    for (int i = 0; i < NSC; ++i) {
      LGKM0(); BAR();
      stage(i);
      VMWAIT(0);
      BAR();
      const int kb = kb_of(i);
      u32x4 wf[8];
      #pragma unroll
      for (int ts = 0; ts < 8; ++ts) {
        const int t = ts >> 1, s = ts & 1;
        unsigned int pq[4];
        #pragma unroll
        for (int e2 = 0; e2 < 4; ++e2) {
          float wa = W[(size_t)(kb + s * 32 + g * 8 + e2 * 2    ) * R_DIM + t * 16 + l4];
          float wb = W[(size_t)(kb + s * 32 + g * 8 + e2 * 2 + 1) * R_DIM + t * 16 + l4];
          pq[e2] = pack2bf(wa, wb);
        }
        wf[ts].x = pq[0]; wf[ts].y = pq[1]; wf[ts].z = pq[2]; wf[ts].w = pq[3];
      }
      compute(i, wf);
    }
  }

  // per-wave K-quarter partials -> LDS [16][72] f32 at wave*4608
  {
    float* part = (float*)(smem + wave * 4608);
    #pragma unroll
    for (int t = 0; t < 4; ++t)
      #pragma unroll
      for (int i = 0; i < 4; ++i)
        part[(g * 4 + i) * 72 + t * 16 + l4] = acc[t][i];
  }
  __syncthreads();   // phase-1 VMEM queue fully drained; full barrier is fine

  // ---------------- Reduce K-quarters + per-row partition mask ------------
  {
    const int row = tid >> 4, jg = tid & 15;
    const float* p0 = (const float*)smem;
    int4 sb = *(const int4*)(subs + (rowbase + row) * 4);
    unsigned mbits = (1u << sb.x) | (1u << sb.y) | (1u << sb.z) | (1u << sb.w);
    unsigned short vals[4];
    #pragma unroll
    for (int jj = 0; jj < 4; ++jj) {
      const int j = jg * 4 + jj;
      float sum = p0[row * 72 + j] + p0[1152 + row * 72 + j] +
                  p0[2304 + row * 72 + j] + p0[3456 + row * 72 + j];
      vals[jj] = ((mbits >> (j >> 3)) & 1u) ? (unsigned short)f2bf_u(sum)
                                            : (unsigned short)0;
    }
    unsigned short* rm = (unsigned short*)(smem + OFF_RM);
    uint2 pk;
    pk.x = (unsigned)vals[0] | ((unsigned)vals[1] << 16);
    pk.y = (unsigned)vals[2] | ((unsigned)vals[3] << 16);
    *(uint2*)(rm + row * 72 + jg * 4) = pk;
  }
  __syncthreads();

  // ---------------- Phase 2: out = base + rm @ W^T ------------------------
  uint4 a2[2];
  #pragma unroll
  for (int s = 0; s < 2; ++s)
    a2[s] = *(const uint4*)(smem + OFF_RM + l4 * 144 + s * 64 + g * 16);

  #pragma unroll 1
  for (int i2 = 0; i2 < NSC; ++i2) {
    const int sc2 = (i2 + off2) & 15;
    const int cb = sc2 * 256;                    // block's 256-col window
    float* cbuf = (float*)(smem + (i2 & 1) * 16384);   // [16][256] f32
    // C[16][cb + wave*64 .. +64] via 8 MFMAs
    #pragma unroll
    for (int t = 0; t < 4; ++t) {
      f32x4v a = (f32x4v){0.f, 0.f, 0.f, 0.f};
      #pragma unroll
      for (int s = 0; s < 2; ++s) {
        uint4 bfrag;
        if (USE_WS) {
          bfrag = *(const uint4*)(Wb_bf +
              (size_t)(cb + wave * 64 + t * 16 + l4) * R_DIM + s * 32 + g * 8);
        } else {
          const float* wp = W + (size_t)(cb + wave * 64 + t * 16 + l4) * R_DIM +
                            s * 32 + g * 8;
          float4 wa = *(const float4*)(wp);
          float4 wc = *(const float4*)(wp + 4);
          bfrag.x = pack2bf(wa.x, wa.y); bfrag.y = pack2bf(wa.z, wa.w);
          bfrag.z = pack2bf(wc.x, wc.y); bfrag.w = pack2bf(wc.z, wc.w);
        }
        a = __builtin_amdgcn_mfma_f32_16x16x32_bf16(
            __builtin_bit_cast(bf16vec8, a2[s]),
            __builtin_bit_cast(bf16vec8, bfrag), a, 0, 0, 0);
      }
      #pragma unroll
      for (int i = 0; i < 4; ++i)
        cbuf[(g * 4 + i) * 256 + wave * 64 + t * 16 + l4] = a[i];
    }
    __syncthreads();
    // contiguous 1KB per instruction: wave stores its 4 rows' 256-col span
    #pragma unroll
    for (int q = 0; q < 4; ++q) {
      const int r = wave * 4 + q;
      const long go = (rowbase + r) * (long)D_DIM + cb + lane * 4;
      f32x4v cv = *(const f32x4v*)(cbuf + r * 256 + lane * 4);
      float4 bb = *(const float4*)(base + go);
      float4 o;
      o.x = cv[0] + bb.x;
      o.y = cv[1] + bb.y;
      o.z = cv[2] + bb.z;
      o.w = cv[3] + bb.w;
      *(float4*)(out + go) = o;
    }
  }
}

extern "C" void kernel_launch(void* const* d_in, const int* in_sizes, int n_in,
                              void* d_out, int out_size, void* d_ws, size_t ws_size,
                              hipStream_t stream) {
  const float* base = (const float*)d_in[0];
  const float* srcp = (const float*)d_in[1];
  const float* W    = (const float*)d_in[2];
  const int*   subs = (const int*)d_in[3];
  float* out = (float*)d_out;

  const int nblocks = 16384 / BM;   // 1024
  const size_t wbytes = (size_t)2 * R_DIM * D_DIM * sizeof(unsigned short); // 1 MB
  if (d_ws && ws_size >= wbytes) {
    unsigned short* Wt = (unsigned short*)d_ws;          // [64][4096] bf16
    unsigned short* Wb = Wt + (size_t)R_DIM * D_DIM;     // [4096][64] bf16
    lrri_prep<<<256, 256, 0, stream>>>(W, Wt, Wb);
    lrri_fused<true><<<nblocks, 256, 0, stream>>>(base, srcp, W, subs, Wt, Wb, out);
  } else {
    lrri_fused<false><<<nblocks, 256, 0, stream>>>(base, srcp, W, subs, nullptr, nullptr, out);
  }
}

// Round 11
// 227.616 us; speedup vs baseline: 1.0707x; 1.0707x over previous
//
#include <hip/hip_runtime.h>

// LowRankRotatedSpaceIntervention — v11 = v10 with the W byte-offset fix.
// out[b,:] = base[b,:] + (mask_b . ((source[b,:]-base[b,:]) @ W)) @ W^T
// B=16384, D=4096, R=64, 8 partitions of 8, 4 selected per row.
//
// v10 failed correctness: Wt_bf is bf16 [64][4096] so column k's byte offset
// is k*2, but stage() used colf*4 — every B-fragment read column 2*colf.
// Swizzle algebra was verified self-canceling; this is the only change.
//
// Experiment (unchanged from R10): phase-1 loop VMEM = global_load_lds ONLY
// (2 base + 2 src + 4 W per 32-col chunk, uniform 8-op ledger), ring-2,
// VMWAIT(8) drains exactly chunk c with c+1 fully in flight. W fragments
// return via ds_read (lgkmcnt queue) => no register load ever drains the
// vmcnt prefetch. Tests whether W-in-the-vmcnt-queue was the 2.9 TB/s cap.

#define D_DIM 4096
#define R_DIM 64
#define BM    32
#define WAVESTG 16384            // per-wave: 2 chunk-slots x 8KB
#define OFF_RM  65536            // [32][72] bf16 = 4608 B
#define SMEM_BYTES 70144         // 2 blocks/CU

typedef short bf16vec8 __attribute__((ext_vector_type(8)));
typedef float f32x4v  __attribute__((ext_vector_type(4)));

#define VMWAIT(N)                                              \
  do {                                                         \
    asm volatile("s_waitcnt vmcnt(" #N ")" ::: "memory");      \
    __builtin_amdgcn_sched_barrier(0);                         \
  } while (0)

__device__ __forceinline__ unsigned int f2bf_u(float f) {
  unsigned int u = __builtin_bit_cast(unsigned int, f);
  return (u + 0x7fffu + ((u >> 16) & 1u)) >> 16;   // RNE
}
__device__ __forceinline__ unsigned int pack2bf(float a, float b) {
  return f2bf_u(a) | (f2bf_u(b) << 16);
}
__device__ __forceinline__ void async_ld16(const void* g, void* l) {
  __builtin_amdgcn_global_load_lds(
      (const __attribute__((address_space(1))) void*)g,
      (__attribute__((address_space(3))) void*)l, 16, 0, 0);
}

__global__ __launch_bounds__(256)
void lrri_prep(const float* __restrict__ W, unsigned short* __restrict__ Wt,
               unsigned short* __restrict__ Wb) {
  const int idx = blockIdx.x * blockDim.x + threadIdx.x;   // 0..65535
  const int k = idx >> 4;
  const int j = (idx & 15) * 4;
  float4 w = *(const float4*)(W + (size_t)k * R_DIM + j);
  ushort4 p;
  p.x = (unsigned short)f2bf_u(w.x);
  p.y = (unsigned short)f2bf_u(w.y);
  p.z = (unsigned short)f2bf_u(w.z);
  p.w = (unsigned short)f2bf_u(w.w);
  *(ushort4*)(Wb + (size_t)k * R_DIM + j) = p;     // [4096][64] bf16
  Wt[(size_t)(j + 0) * D_DIM + k] = p.x;           // [64][4096] bf16
  Wt[(size_t)(j + 1) * D_DIM + k] = p.y;
  Wt[(size_t)(j + 2) * D_DIM + k] = p.z;
  Wt[(size_t)(j + 3) * D_DIM + k] = p.w;
}

template<bool USE_WS>
__global__ __launch_bounds__(256, 2)
void lrri_fused(const float* __restrict__ base, const float* __restrict__ srcp,
                const float* __restrict__ W, const int* __restrict__ subs,
                const unsigned short* __restrict__ Wt_bf,   // [64][4096]
                const unsigned short* __restrict__ Wb_bf,   // [4096][64]
                float* __restrict__ out)
{
  __shared__ __align__(16) unsigned char smem[SMEM_BYTES];
  const int tid  = threadIdx.x;
  const int wave = tid >> 6;
  const int lane = tid & 63;
  const int l4   = lane & 15;
  const int g    = lane >> 4;
  const int rh   = wave >> 1;            // row-half: 16 rows
  const int kh   = wave & 1;             // K-half: 2048 cols
  const long rowbase = (long)blockIdx.x * BM;
  const long rowg    = rowbase + rh * 16;
  unsigned char* wbuf = smem + wave * WAVESTG;
  const int off1 = (blockIdx.x * 7) & 63;   // phase-1 chunk stagger
  const int off2 = (blockIdx.x * 5) & 15;   // phase-2 group stagger

  // ---------------- Phase 1: r = (src-base) @ W over this wave's K half ---
  // chunk = 32 cols. Slot layout (8KB): [0,2KB) base [16r][128B],
  // [2KB,4KB) src, [4KB,8KB) W slice [64j][64B]. All XOR-swizzled at source.
  f32x4v acc[4];
  #pragma unroll
  for (int t = 0; t < 4; ++t) acc[t] = (f32x4v){0.f, 0.f, 0.f, 0.f};

  auto stage = [&](int c) {                       // 8 gload_lds, order-pinned
    const int ch = (c + off1) & 63;               // rotated chunk id
    unsigned char* buf = wbuf + (c & 1) * 8192;
    const long colf = kh * 2048 + ch * 32;        // first float col
    // base+src: 2 instrs each; instr q covers rows 8q..8q+7 x 128B
    #pragma unroll
    for (int q = 0; q < 2; ++q) {
      const int r = q * 8 + (lane >> 3);          // row_local
      const unsigned b = ((unsigned)((lane & 7) * 16)) ^ ((unsigned)(r & 7) << 4);
      const long goff = (rowg + r) * (long)D_DIM + colf + (b >> 2);
      async_ld16(base + goff, buf + q * 1024);
    }
    #pragma unroll
    for (int q = 0; q < 2; ++q) {
      const int r = q * 8 + (lane >> 3);
      const unsigned b = ((unsigned)((lane & 7) * 16)) ^ ((unsigned)(r & 7) << 4);
      const long goff = (rowg + r) * (long)D_DIM + colf + (b >> 2);
      async_ld16(srcp + goff, buf + 2048 + q * 1024);
    }
    // W slice [64j][32k bf16 = 64B]: 4 instrs; instr q covers j-rows 16q..+15
    // byte offset of column k in Wt_bf row = k*2  (v10 bug: used colf*4)
    #pragma unroll
    for (int q = 0; q < 4; ++q) {
      const int j = q * 16 + (lane >> 2);
      const unsigned kb = ((unsigned)((lane & 3) * 16)) ^ ((unsigned)(j & 3) << 4);
      const char* src = (const char*)Wt_bf + (size_t)j * (D_DIM * 2) +
                        colf * 2 + kb;
      async_ld16(src, buf + 4096 + q * 1024);
    }
  };

  auto compute = [&](int c) {
    const unsigned char* buf = wbuf + (c & 1) * 8192;
    const unsigned sw = (unsigned)((l4 & 7) << 4);
    const unsigned c0 = ((unsigned)(g * 32)) ^ sw;
    const unsigned c1 = ((unsigned)(g * 32 + 16)) ^ sw;
    float4 fb0 = *(const float4*)(buf + l4 * 128 + c0);
    float4 fb1 = *(const float4*)(buf + l4 * 128 + c1);
    float4 fs0 = *(const float4*)(buf + 2048 + l4 * 128 + c0);
    float4 fs1 = *(const float4*)(buf + 2048 + l4 * 128 + c1);
    uint4 af;
    af.x = pack2bf(fs0.x - fb0.x, fs0.y - fb0.y);
    af.y = pack2bf(fs0.z - fb0.z, fs0.w - fb0.w);
    af.z = pack2bf(fs1.x - fb1.x, fs1.y - fb1.y);
    af.w = pack2bf(fs1.z - fb1.z, fs1.w - fb1.w);
    const unsigned wsl = ((unsigned)(g * 16)) ^ ((unsigned)(l4 & 3) << 4);
    #pragma unroll
    for (int t = 0; t < 4; ++t) {
      uint4 wf = *(const uint4*)(buf + 4096 + (t * 16 + l4) * 64 + wsl);
      acc[t] = __builtin_amdgcn_mfma_f32_16x16x32_bf16(
          __builtin_bit_cast(bf16vec8, af),
          __builtin_bit_cast(bf16vec8, wf), acc[t], 0, 0, 0);
    }
  };

  if constexpr (USE_WS) {
    stage(0); stage(1);                 // queue: 16
    #pragma unroll 1
    for (int c = 0; c < 62; ++c) {
      VMWAIT(8);                        // drains chunk c exactly
      compute(c);                       // MFMA lgkm-dep proves ds_reads done
      __builtin_amdgcn_sched_barrier(0);
      stage(c + 2);                     // refill slot (c&1)
    }
    VMWAIT(8);
    compute(62);
    VMWAIT(0);
    compute(63);
  } else {
    // fallback: serial full-drain; W from fp32 global via registers
    #pragma unroll 1
    for (int c = 0; c < 64; ++c) {
      const int ch = (c + off1) & 63;
      unsigned char* buf = wbuf + (c & 1) * 8192;
      const long colf = kh * 2048 + ch * 32;
      #pragma unroll
      for (int q = 0; q < 2; ++q) {
        const int r = q * 8 + (lane >> 3);
        const unsigned b = ((unsigned)((lane & 7) * 16)) ^ ((unsigned)(r & 7) << 4);
        const long goff = (rowg + r) * (long)D_DIM + colf + (b >> 2);
        async_ld16(base + goff, buf + q * 1024);
        async_ld16(srcp + goff, buf + 2048 + q * 1024);
      }
      VMWAIT(0);
      const unsigned sw = (unsigned)((l4 & 7) << 4);
      const unsigned c0 = ((unsigned)(g * 32)) ^ sw;
      const unsigned c1 = ((unsigned)(g * 32 + 16)) ^ sw;
      float4 fb0 = *(const float4*)(buf + l4 * 128 + c0);
      float4 fb1 = *(const float4*)(buf + l4 * 128 + c1);
      float4 fs0 = *(const float4*)(buf + 2048 + l4 * 128 + c0);
      float4 fs1 = *(const float4*)(buf + 2048 + l4 * 128 + c1);
      uint4 af;
      af.x = pack2bf(fs0.x - fb0.x, fs0.y - fb0.y);
      af.y = pack2bf(fs0.z - fb0.z, fs0.w - fb0.w);
      af.z = pack2bf(fs1.x - fb1.x, fs1.y - fb1.y);
      af.w = pack2bf(fs1.z - fb1.z, fs1.w - fb1.w);
      #pragma unroll
      for (int t = 0; t < 4; ++t) {
        unsigned int pq[4];
        #pragma unroll
        for (int e2 = 0; e2 < 4; ++e2) {
          float wa = W[(size_t)(colf + g * 8 + e2 * 2    ) * R_DIM + t * 16 + l4];
          float wb = W[(size_t)(colf + g * 8 + e2 * 2 + 1) * R_DIM + t * 16 + l4];
          pq[e2] = pack2bf(wa, wb);
        }
        uint4 wf; wf.x = pq[0]; wf.y = pq[1]; wf.z = pq[2]; wf.w = pq[3];
        acc[t] = __builtin_amdgcn_mfma_f32_16x16x32_bf16(
            __builtin_bit_cast(bf16vec8, af),
            __builtin_bit_cast(bf16vec8, wf), acc[t], 0, 0, 0);
      }
    }
  }

  // per-wave partials -> own staging area (dead now): [16][72] f32
  {
    float* part = (float*)wbuf;
    #pragma unroll
    for (int t = 0; t < 4; ++t)
      #pragma unroll
      for (int i = 0; i < 4; ++i)
        part[(g * 4 + i) * 72 + t * 16 + l4] = acc[t][i];
  }
  __syncthreads();

  // ---------------- Reduce K-halves + per-row partition mask --------------
  {
    const int row = tid >> 3, jg = tid & 7;     // 32 rows x 8 j-groups
    const int lr  = row & 15;
    const float* pa = (const float*)(smem + ((row >> 4) * 2 + 0) * WAVESTG);
    const float* pb = (const float*)(smem + ((row >> 4) * 2 + 1) * WAVESTG);
    int4 sb = *(const int4*)(subs + (rowbase + row) * 4);
    unsigned mbits = (1u << sb.x) | (1u << sb.y) | (1u << sb.z) | (1u << sb.w);
    unsigned short v[8];
    #pragma unroll
    for (int jj = 0; jj < 8; ++jj) {
      const int j = jg * 8 + jj;
      float sum = pa[lr * 72 + j] + pb[lr * 72 + j];
      v[jj] = ((mbits >> (j >> 3)) & 1u) ? (unsigned short)f2bf_u(sum)
                                         : (unsigned short)0;
    }
    uint4 pk;
    pk.x = (unsigned)v[0] | ((unsigned)v[1] << 16);
    pk.y = (unsigned)v[2] | ((unsigned)v[3] << 16);
    pk.z = (unsigned)v[4] | ((unsigned)v[5] << 16);
    pk.w = (unsigned)v[6] | ((unsigned)v[7] << 16);
    *(uint4*)(smem + OFF_RM + row * 144 + jg * 16) = pk;   // stride 72 shorts
  }
  __syncthreads();

  // ---------------- Phase 2: out = base(global) + rm @ W^T (v8 verbatim) --
  uint4 a2[2][2];     // [row-tile m][k-split s]
  #pragma unroll
  for (int m = 0; m < 2; ++m)
    #pragma unroll
    for (int s = 0; s < 2; ++s)
      a2[m][s] = *(const uint4*)(smem + OFF_RM + (m * 16 + l4) * 144 +
                                 s * 64 + g * 16);
  float* cbuf = (float*)wbuf;     // [32][72] f32 = 9216 B, wave-private
  #pragma unroll 1
  for (int grp = 0; grp < 16; ++grp) {
    const int ga = (grp + off2) & 15;           // rotated column group
    const int cbase = wave * 1024 + ga * 64;
    float4 bb[8];
    #pragma unroll
    for (int v2 = 0; v2 < 8; ++v2) {
      const int r = g + v2 * 4;
      bb[v2] = *(const float4*)(base + (rowbase + r) * D_DIM + cbase + l4 * 4);
    }
    f32x4v a[2][4];
    #pragma unroll
    for (int m = 0; m < 2; ++m)
      #pragma unroll
      for (int t = 0; t < 4; ++t) a[m][t] = (f32x4v){0.f, 0.f, 0.f, 0.f};
    #pragma unroll
    for (int t = 0; t < 4; ++t) {
      #pragma unroll
      for (int s = 0; s < 2; ++s) {
        uint4 bfrag;  // B[kk=j][n=col] = W[col][j]
        if (USE_WS) {
          bfrag = *(const uint4*)(Wb_bf + (size_t)(cbase + t * 16 + l4) * R_DIM +
                                  s * 32 + g * 8);
        } else {
          const float* wp = W + (size_t)(cbase + t * 16 + l4) * R_DIM + s * 32 + g * 8;
          float4 wa = *(const float4*)(wp);
          float4 wb2 = *(const float4*)(wp + 4);
          bfrag.x = pack2bf(wa.x, wa.y); bfrag.y = pack2bf(wa.z, wa.w);
          bfrag.z = pack2bf(wb2.x, wb2.y); bfrag.w = pack2bf(wb2.z, wb2.w);
        }
        #pragma unroll
        for (int m = 0; m < 2; ++m)
          a[m][t] = __builtin_amdgcn_mfma_f32_16x16x32_bf16(
              __builtin_bit_cast(bf16vec8, a2[m][s]),
              __builtin_bit_cast(bf16vec8, bfrag), a[m][t], 0, 0, 0);
      }
    }
    #pragma unroll
    for (int m = 0; m < 2; ++m)
      #pragma unroll
      for (int t = 0; t < 4; ++t)
        #pragma unroll
        for (int i = 0; i < 4; ++i)
          cbuf[(m * 16 + g * 4 + i) * 72 + t * 16 + l4] = a[m][t][i];
    #pragma unroll
    for (int v2 = 0; v2 < 8; ++v2) {
      const int r = g + v2 * 4;
      f32x4v cv = *(const f32x4v*)(cbuf + r * 72 + l4 * 4);
      float4 o;
      o.x = cv[0] + bb[v2].x;
      o.y = cv[1] + bb[v2].y;
      o.z = cv[2] + bb[v2].z;
      o.w = cv[3] + bb[v2].w;
      *(float4*)(out + (rowbase + r) * D_DIM + cbase + l4 * 4) = o;
    }
  }
}

extern "C" void kernel_launch(void* const* d_in, const int* in_sizes, int n_in,
                              void* d_out, int out_size, void* d_ws, size_t ws_size,
                              hipStream_t stream) {
  const float* base = (const float*)d_in[0];
  const float* srcp = (const float*)d_in[1];
  const float* W    = (const float*)d_in[2];
  const int*   subs = (const int*)d_in[3];
  float* out = (float*)d_out;

  const int nblocks = 16384 / BM;   // 512
  const size_t wbytes = (size_t)2 * R_DIM * D_DIM * sizeof(unsigned short); // 1 MB
  if (d_ws && ws_size >= wbytes) {
    unsigned short* Wt = (unsigned short*)d_ws;          // [64][4096] bf16
    unsigned short* Wb = Wt + (size_t)R_DIM * D_DIM;     // [4096][64] bf16
    lrri_prep<<<256, 256, 0, stream>>>(W, Wt, Wb);
    lrri_fused<true><<<nblocks, 256, 0, stream>>>(base, srcp, W, subs, Wt, Wb, out);
  } else {
    lrri_fused<false><<<nblocks, 256, 0, stream>>>(base, srcp, W, subs, nullptr, nullptr, out);
  }
}